// Round 3
// baseline (108.868 us; speedup 1.0000x reference)
//
#include <hip/hip_runtime.h>
#include <hip/hip_bf16.h>

// Max-unpool 2x2 stride 2, NHWC fp32.
// Input:  inputs  (8,112,112,256) f32, indices (8,112,112,256) i32 in {0..3}
// Output: (8,224,224,256) f32.
// index k -> (di,dj) = (k>>1, k&1); out[n][2h+di][2w+dj][d] = in, others 0.
//
// One thread per 4 input float4s (exact-fit grid, no tail). All 8 loads
// issued up front (8 outstanding VMEM/thread). Non-temporal loads/stores:
// pure 617 MB stream, zero reuse -> bypass L2 allocation. Every output byte
// written exactly once; all accesses coalesced (each wave = one pixel's 256
// floats contiguous; o0/o1 store pairs form 2 KB contiguous runs).

typedef float f32x4 __attribute__((ext_vector_type(4)));
typedef int   i32x4 __attribute__((ext_vector_type(4)));

#define W_ROW   128      // float4 stride of one 2w step: 2*64
#define H_ROW   28672    // float4 stride of one input-h step: 224*64*2
#define N_IMG   3211264  // float4 stride of one image: 224*224*64
#define OUT_ROW 14336    // float4 stride of one output row: 224*64

__device__ __forceinline__ void masked4(const f32x4& val, const i32x4& ix, int k, f32x4& o) {
    o[0] = (ix[0] == k) ? val[0] : 0.0f;
    o[1] = (ix[1] == k) ? val[1] : 0.0f;
    o[2] = (ix[2] == k) ? val[2] : 0.0f;
    o[3] = (ix[3] == k) ? val[3] : 0.0f;
}

__device__ __forceinline__ void scatter_one(f32x4* __restrict__ out, int v,
                                            const f32x4& val, const i32x4& ix) {
    int dvec = v & 63;
    int rest = v >> 6;             // (n*112 + h)*112 + w
    int w    = rest % 112;
    int hn   = rest / 112;
    int h    = hn % 112;
    int n    = hn / 112;
    int base = n * N_IMG + h * H_ROW + w * W_ROW + dvec;

    f32x4 o0, o1, o2, o3;
    masked4(val, ix, 0, o0);
    masked4(val, ix, 1, o1);
    masked4(val, ix, 2, o2);
    masked4(val, ix, 3, o3);

    // row 2h: 2 KB contiguous pair; row 2h+1: 2 KB contiguous pair
    __builtin_nontemporal_store(o0, out + base);                 // (0,0)
    __builtin_nontemporal_store(o1, out + base + 64);            // (0,1)
    __builtin_nontemporal_store(o2, out + base + OUT_ROW);       // (1,0)
    __builtin_nontemporal_store(o3, out + base + OUT_ROW + 64);  // (1,1)
}

__global__ __launch_bounds__(256) void maxunpool_kernel(
    const f32x4* __restrict__ in,
    const i32x4* __restrict__ idx,
    f32x4* __restrict__ out)
{
    int v0 = blockIdx.x * 1024 + threadIdx.x;   // 4 float4s per thread
    int v1 = v0 + 256;
    int v2 = v0 + 512;
    int v3 = v0 + 768;

    // Issue all 8 loads before any compute (MLP).
    f32x4 a0 = __builtin_nontemporal_load(in + v0);
    i32x4 x0 = __builtin_nontemporal_load(idx + v0);
    f32x4 a1 = __builtin_nontemporal_load(in + v1);
    i32x4 x1 = __builtin_nontemporal_load(idx + v1);
    f32x4 a2 = __builtin_nontemporal_load(in + v2);
    i32x4 x2 = __builtin_nontemporal_load(idx + v2);
    f32x4 a3 = __builtin_nontemporal_load(in + v3);
    i32x4 x3 = __builtin_nontemporal_load(idx + v3);

    scatter_one(out, v0, a0, x0);
    scatter_one(out, v1, a1, x1);
    scatter_one(out, v2, a2, x2);
    scatter_one(out, v3, a3, x3);
}

extern "C" void kernel_launch(void* const* d_in, const int* in_sizes, int n_in,
                              void* d_out, int out_size, void* d_ws, size_t ws_size,
                              hipStream_t stream) {
    const f32x4* in  = (const f32x4*)d_in[0];
    const i32x4* idx = (const i32x4*)d_in[1];
    f32x4*       out = (f32x4*)d_out;

    // nvec = 8*112*112*64 = 6,422,528 float4s = 6272 blocks * 1024 exactly.
    int grid = 6272;
    maxunpool_kernel<<<grid, 256, 0, stream>>>(in, idx, out);
}

// Round 4
// 107.164 us; speedup vs baseline: 1.0159x; 1.0159x over previous
//
#include <hip/hip_runtime.h>
#include <hip/hip_bf16.h>

// Max-unpool 2x2 stride 2, NHWC fp32.
// Input:  inputs  (8,112,112,256) f32, indices (8,112,112,256) i32 in {0..3}
// Output: (8,224,224,256) f32.
// index k -> (di,dj) = (k>>1, k&1); out[n][2h+di][2w+dj][d] = in, others 0.
//
// FINAL (round-2 config, best measured: 106.3 us = 5.8 TB/s on the 617 MB
// minimum stream; 1:2 read:write mix, ceiling band ~6.3-6.9 TB/s).
// One thread per 2 input float4s (exact-fit grid, no tail). All 4 loads
// issued up front. Non-temporal loads/stores (pure stream, zero reuse ->
// bypass L2 allocation). Every output byte written exactly once; all
// accesses coalesced (each wave = one pixel's 256 floats contiguous;
// o0/o1 store pairs form 2 KB contiguous runs).
// Probed and rejected: grid-stride@2048 (119 us), 4 float4/thread (109 us).

typedef float f32x4 __attribute__((ext_vector_type(4)));
typedef int   i32x4 __attribute__((ext_vector_type(4)));

#define W_ROW   128      // float4 stride of one 2w step: 2*64
#define H_ROW   28672    // float4 stride of one input-h step: 224*64*2
#define N_IMG   3211264  // float4 stride of one image: 224*224*64
#define OUT_ROW 14336    // float4 stride of one output row: 224*64

__device__ __forceinline__ void masked4(const f32x4& val, const i32x4& ix, int k, f32x4& o) {
    o[0] = (ix[0] == k) ? val[0] : 0.0f;
    o[1] = (ix[1] == k) ? val[1] : 0.0f;
    o[2] = (ix[2] == k) ? val[2] : 0.0f;
    o[3] = (ix[3] == k) ? val[3] : 0.0f;
}

__device__ __forceinline__ void scatter_one(f32x4* __restrict__ out, int v,
                                            const f32x4& val, const i32x4& ix) {
    int dvec = v & 63;
    int rest = v >> 6;             // (n*112 + h)*112 + w
    int w    = rest % 112;
    int hn   = rest / 112;
    int h    = hn % 112;
    int n    = hn / 112;
    int base = n * N_IMG + h * H_ROW + w * W_ROW + dvec;

    f32x4 o0, o1, o2, o3;
    masked4(val, ix, 0, o0);
    masked4(val, ix, 1, o1);
    masked4(val, ix, 2, o2);
    masked4(val, ix, 3, o3);

    __builtin_nontemporal_store(o0, out + base);                 // (0,0)
    __builtin_nontemporal_store(o1, out + base + 64);            // (0,1)
    __builtin_nontemporal_store(o2, out + base + OUT_ROW);       // (1,0)
    __builtin_nontemporal_store(o3, out + base + OUT_ROW + 64);  // (1,1)
}

__global__ __launch_bounds__(256) void maxunpool_kernel(
    const f32x4* __restrict__ in,
    const i32x4* __restrict__ idx,
    f32x4* __restrict__ out)
{
    int v0 = blockIdx.x * 512 + threadIdx.x;   // first float4
    int v1 = v0 + 256;                         // second float4

    // Issue all 4 loads before any compute (MLP).
    f32x4 val0 = __builtin_nontemporal_load(in + v0);
    i32x4 ix0  = __builtin_nontemporal_load(idx + v0);
    f32x4 val1 = __builtin_nontemporal_load(in + v1);
    i32x4 ix1  = __builtin_nontemporal_load(idx + v1);

    scatter_one(out, v0, val0, ix0);
    scatter_one(out, v1, val1, ix1);
}

extern "C" void kernel_launch(void* const* d_in, const int* in_sizes, int n_in,
                              void* d_out, int out_size, void* d_ws, size_t ws_size,
                              hipStream_t stream) {
    const f32x4* in  = (const f32x4*)d_in[0];
    const i32x4* idx = (const i32x4*)d_in[1];
    f32x4*       out = (f32x4*)d_out;

    // nvec = 8*112*112*64 = 6,422,528 float4s = 12544 blocks * 512 exactly.
    int grid = 12544;
    maxunpool_kernel<<<grid, 256, 0, stream>>>(in, idx, out);
}